// Round 1
// baseline (450.826 us; speedup 1.0000x reference)
//
#include <hip/hip_runtime.h>

// HebbLinear fused kernel.
// Shapes: x(1,256,512) f32, hebb(256,512,512) f32, w(512,512) f32,
//         b(512) f32, alpha(512) f32.
// out = [ y(256*512) | delta(256*512*512) ] flat f32.
//
// y[b,o]     = sum_i x[b,i]*w[i,o] + (x[b,i]*alpha[i])*hebb[b,i,o] + bias[o]
// delta[b,i,o] = x[b,i] * y[b,o]
//
// HBM traffic: read hebb 268 MB + write delta 268 MB -> ~85 us floor @6.3 TB/s.
// One block per sample: 256 blocks (1/CU), 512 threads (8 waves/CU).
// Thread (oq = tid&127, ip = tid>>7): float4 over o, strided-by-4 over i.

#define IND  512
#define OUTD 512
#define BSZ  256
#define OQ   (OUTD / 4)   // 128 float4 groups along o

__global__ __launch_bounds__(512, 1) void hebb_fused(
    const float* __restrict__ x,
    const float* __restrict__ hebb,
    const float* __restrict__ w,
    const float* __restrict__ bias,
    const float* __restrict__ alpha,
    float* __restrict__ out)
{
    const int b   = blockIdx.x;
    const int tid = threadIdx.x;
    const int oq  = tid & (OQ - 1);   // which float4 along o
    const int ip  = tid >> 7;         // i-phase 0..3

    __shared__ float  x_s[IND];
    __shared__ float  xa_s[IND];
    __shared__ float4 red_s[4][OQ];   // 8 KB partial-sum exchange
    __shared__ float4 y_s[OQ];        // final y for phase 2

    // Stage x[b,:] and x[b,:]*alpha[:] (512 threads, 1 elem each)
    {
        const float xv = x[b * IND + tid];
        x_s[tid]  = xv;
        xa_s[tid] = xv * alpha[tid];
    }
    __syncthreads();

    const float4* __restrict__ hb4 = (const float4*)hebb + (size_t)b * (IND * OQ);
    const float4* __restrict__ w4  = (const float4*)w;

    // Phase 1: batched GEMV, 16B/lane coalesced streams of hebb (HBM) and w (L2-resident)
    float4 acc = make_float4(0.f, 0.f, 0.f, 0.f);
#pragma unroll 4
    for (int i = ip; i < IND; i += 4) {
        const float  xs = x_s[i];    // LDS broadcast (same addr all lanes: free)
        const float  xa = xa_s[i];
        const float4 wv = w4[i * OQ + oq];
        const float4 hv = hb4[i * OQ + oq];
        acc.x = fmaf(xa, hv.x, fmaf(xs, wv.x, acc.x));
        acc.y = fmaf(xa, hv.y, fmaf(xs, wv.y, acc.y));
        acc.z = fmaf(xa, hv.z, fmaf(xs, wv.z, acc.z));
        acc.w = fmaf(xa, hv.w, fmaf(xs, wv.w, acc.w));
    }
    red_s[ip][oq] = acc;
    __syncthreads();

    // Reduce the 4 i-phases, add bias, emit y
    if (ip == 0) {
        const float4 a0 = red_s[0][oq];
        const float4 a1 = red_s[1][oq];
        const float4 a2 = red_s[2][oq];
        const float4 a3 = red_s[3][oq];
        const float4 bv = ((const float4*)bias)[oq];
        float4 y;
        y.x = (a0.x + a1.x) + (a2.x + a3.x) + bv.x;
        y.y = (a0.y + a1.y) + (a2.y + a3.y) + bv.y;
        y.z = (a0.z + a1.z) + (a2.z + a3.z) + bv.z;
        y.w = (a0.w + a1.w) + (a2.w + a3.w) + bv.w;
        y_s[oq] = y;
        ((float4*)out)[b * OQ + oq] = y;   // output 0: y, flat [b*512 + o]
    }
    __syncthreads();

    // Phase 2: delta[b,i,o] = x[b,i] * y[b,o] — pure coalesced float4 store stream
    const float4 y = y_s[oq];
    float4* __restrict__ delta4 = (float4*)(out + BSZ * OUTD) + (size_t)b * (IND * OQ);
#pragma unroll 4
    for (int i = ip; i < IND; i += 4) {
        const float xs = x_s[i];
        float4 dv;
        dv.x = xs * y.x;
        dv.y = xs * y.y;
        dv.z = xs * y.z;
        dv.w = xs * y.w;
        delta4[i * OQ + oq] = dv;
    }
}

extern "C" void kernel_launch(void* const* d_in, const int* in_sizes, int n_in,
                              void* d_out, int out_size, void* d_ws, size_t ws_size,
                              hipStream_t stream)
{
    const float* x     = (const float*)d_in[0];
    const float* hebb  = (const float*)d_in[1];
    const float* w     = (const float*)d_in[2];
    const float* bias  = (const float*)d_in[3];
    const float* alpha = (const float*)d_in[4];
    float* out = (float*)d_out;

    hipLaunchKernelGGL(hebb_fused, dim3(BSZ), dim3(512), 0, stream,
                       x, hebb, w, bias, alpha, out);
}

// Round 2
// 428.029 us; speedup vs baseline: 1.0533x; 1.0533x over previous
//
#include <hip/hip_runtime.h>

// HebbLinear fused kernel, round 2.
// y[b,o] = sum_i x[b,i]*w[i,o] + (x[b,i]*alpha[i])*hebb[b,i,o] + bias[o]
// delta[b,i,o] = x[b,i]*y[b,o]
// out = [ y (256*512) | delta (256*512*512) ] flat f32.
//
// HBM floor: hebb read 268 MB + delta write 268 MB ≈ 85 us @ 6.3 TB/s.
// 256 blocks (1/CU) x 512 threads. Thread (oq=tid&127, ip=tid>>7).
// R2 changes vs R1: nontemporal on the zero-reuse streams (hebb in,
// delta/y out) to keep w/bias L2-resident; unroll 8 (16 loads in flight);
// x and x*alpha packed into one float2 LDS broadcast.

typedef float v4f __attribute__((ext_vector_type(4)));
typedef float v2f __attribute__((ext_vector_type(2)));

#define IND  512
#define OUTD 512
#define BSZ  256
#define OQ   (OUTD / 4)   // 128 float4 groups along o

__global__ __launch_bounds__(512, 2) void hebb_fused(
    const float* __restrict__ x,
    const float* __restrict__ hebb,
    const float* __restrict__ w,
    const float* __restrict__ bias,
    const float* __restrict__ alpha,
    float* __restrict__ out)
{
    const int b   = blockIdx.x;
    const int tid = threadIdx.x;
    const int oq  = tid & (OQ - 1);   // float4 index along o
    const int ip  = tid >> 7;         // i-phase 0..3

    __shared__ v2f x2_s[IND];         // {x[i], x[i]*alpha[i]}
    __shared__ v4f red_s[4][OQ];      // 8 KB partial-sum exchange
    __shared__ v4f y_s[OQ];           // final y for phase 2

    // Stage x and x*alpha (512 threads, 1 elem each)
    {
        const float xv = x[b * IND + tid];
        v2f t;
        t.x = xv;
        t.y = xv * alpha[tid];
        x2_s[tid] = t;
    }
    __syncthreads();

    const v4f* __restrict__ hb4 = (const v4f*)hebb + (size_t)b * (IND * OQ);
    const v4f* __restrict__ w4  = (const v4f*)w;

    // Phase 1: batched GEMV. hebb is a zero-reuse HBM stream -> nontemporal;
    // w is reused by all 256 blocks -> normal (L2-resident).
    v4f acc = 0.0f;
#pragma unroll 8
    for (int i = ip; i < IND; i += 4) {
        const v2f xx = x2_s[i];       // one ds_read_b64, same-addr broadcast
        const v4f wv = w4[i * OQ + oq];
        const v4f hv = __builtin_nontemporal_load(&hb4[i * OQ + oq]);
        acc += xx.x * wv + xx.y * hv; // contracts to v_fma_f32
    }
    red_s[ip][oq] = acc;
    __syncthreads();

    // Reduce 4 i-phases, add bias, emit y
    if (ip == 0) {
        v4f y = (red_s[0][oq] + red_s[1][oq]) + (red_s[2][oq] + red_s[3][oq])
              + ((const v4f*)bias)[oq];
        y_s[oq] = y;
        __builtin_nontemporal_store(y, (v4f*)out + b * OQ + oq);
    }
    __syncthreads();

    // Phase 2: delta[b,i,o] = x[i]*y[o] — zero-reuse write stream, nontemporal
    const v4f y = y_s[oq];
    v4f* __restrict__ delta4 = (v4f*)(out + BSZ * OUTD) + (size_t)b * (IND * OQ);
#pragma unroll 8
    for (int i = ip; i < IND; i += 4) {
        const float xs = x2_s[i].x;
        __builtin_nontemporal_store(xs * y, &delta4[i * OQ + oq]);
    }
}

extern "C" void kernel_launch(void* const* d_in, const int* in_sizes, int n_in,
                              void* d_out, int out_size, void* d_ws, size_t ws_size,
                              hipStream_t stream)
{
    const float* x     = (const float*)d_in[0];
    const float* hebb  = (const float*)d_in[1];
    const float* w     = (const float*)d_in[2];
    const float* bias  = (const float*)d_in[3];
    const float* alpha = (const float*)d_in[4];
    float* out = (float*)d_out;

    hipLaunchKernelGGL(hebb_fused, dim3(BSZ), dim3(512), 0, stream,
                       x, hebb, w, bias, alpha, out);
}